// Round 2
// baseline (172.942 us; speedup 1.0000x reference)
//
#include <hip/hip_runtime.h>

#define BB 4
#define NN 2048
#define FF 512
#define ALPHA 0.2f

typedef unsigned short u16;
typedef unsigned char u8;
typedef unsigned int u32;
typedef __attribute__((ext_vector_type(8))) short bf16x8;
typedef __attribute__((ext_vector_type(4))) float f32x4;

__device__ __forceinline__ u16 f2bf(float x) {
  union { float f; u32 u; } v; v.f = x;
  u32 r = v.u + 0x7fffu + ((v.u >> 16) & 1u);
  return (u16)(r >> 16);
}
__device__ __forceinline__ float leaky(float x) { return x >= 0.f ? x : ALPHA * x; }

// -------------------------------------------------------------------------
// K1: whT[b][f][i] = (h@W)^T in bf16  +  fused s1/s2 (from fp32 acc, atomics)
// A-operand = W^T rows (f), B-operand = h rows (i)  =>  D: row=f, col=i
// grid (64 m-tiles, 4 f-tiles), 256 threads, wave tile 64f x 64i
// -------------------------------------------------------------------------
__global__ __launch_bounds__(256) void k_wh(const float* __restrict__ h,
                                            const float* __restrict__ W,
                                            const float* __restrict__ a,
                                            u16* __restrict__ whT,
                                            float* __restrict__ s1,
                                            float* __restrict__ s2) {
  __shared__ __attribute__((aligned(16))) u16 As[128][40];  // h rows [i][k]
  __shared__ __attribute__((aligned(16))) u16 Bs[128][40];  // W^T rows [f][k]
  const int m0 = blockIdx.x * 128, f0 = blockIdx.y * 128;
  const int tid = threadIdx.x, wave = tid >> 6, lane = tid & 63;
  const int wf = (wave >> 1) * 64, wi = (wave & 1) * 64;

  f32x4 acc[4][4];
#pragma unroll
  for (int x = 0; x < 4; x++)
#pragma unroll
    for (int y = 0; y < 4; y++) acc[x][y] = f32x4{0.f, 0.f, 0.f, 0.f};

  for (int k0 = 0; k0 < FF; k0 += 32) {
    {
      const int kc = tid & 7, ib = tid >> 3;
#pragma unroll
      for (int p = 0; p < 4; p++) {
        const int i = ib + p * 32;
        float4 v = *(const float4*)(h + (size_t)(m0 + i) * FF + k0 + kc * 4);
        ushort4 o; o.x = f2bf(v.x); o.y = f2bf(v.y); o.z = f2bf(v.z); o.w = f2bf(v.w);
        *(ushort4*)(&As[i][kc * 4]) = o;
      }
    }
    {
      const int fc = tid & 31, kb = tid >> 5;
#pragma unroll
      for (int p = 0; p < 4; p++) {
        const int k = kb + p * 8;
        float4 v = *(const float4*)(W + (size_t)(k0 + k) * FF + f0 + fc * 4);
        Bs[fc * 4 + 0][k] = f2bf(v.x);
        Bs[fc * 4 + 1][k] = f2bf(v.y);
        Bs[fc * 4 + 2][k] = f2bf(v.z);
        Bs[fc * 4 + 3][k] = f2bf(v.w);
      }
    }
    __syncthreads();
    {
      const int r = lane & 15, kq = lane >> 4;
      bf16x8 wfr[4], hfr[4];
#pragma unroll
      for (int fi = 0; fi < 4; fi++) wfr[fi] = *(const bf16x8*)(&Bs[wf + fi * 16 + r][kq * 8]);
#pragma unroll
      for (int ii = 0; ii < 4; ii++) hfr[ii] = *(const bf16x8*)(&As[wi + ii * 16 + r][kq * 8]);
#pragma unroll
      for (int fi = 0; fi < 4; fi++)
#pragma unroll
        for (int ii = 0; ii < 4; ii++)
          acc[fi][ii] = __builtin_amdgcn_mfma_f32_16x16x32_bf16(wfr[fi], hfr[ii], acc[fi][ii], 0, 0, 0);
    }
    __syncthreads();
  }

  const int b = m0 >> 11, ibase = m0 & (NN - 1);
  const int r = lane & 15, rg = lane >> 4;
  float a1v[16], a2v[16];
#pragma unroll
  for (int fi = 0; fi < 4; fi++)
#pragma unroll
    for (int rr = 0; rr < 4; rr++) {
      const int f = f0 + wf + fi * 16 + rg * 4 + rr;
      a1v[fi * 4 + rr] = a[f];
      a2v[fi * 4 + rr] = a[FF + f];
    }
  // whT store: D row=f (rg*4+rr), col=i (lane&15) -> 32B-contiguous segments
#pragma unroll
  for (int fi = 0; fi < 4; fi++)
#pragma unroll
    for (int ii = 0; ii < 4; ii++)
#pragma unroll
      for (int rr = 0; rr < 4; rr++) {
        const int f = f0 + wf + fi * 16 + rg * 4 + rr;
        whT[((size_t)b * FF + f) * NN + ibase + wi + ii * 16 + r] = f2bf(acc[fi][ii][rr]);
      }
  // fused s1/s2: per-lane partial over its 16 f's, butterfly over lane>>4 groups
#pragma unroll
  for (int ii = 0; ii < 4; ii++) {
    float p1 = 0.f, p2 = 0.f;
#pragma unroll
    for (int fi = 0; fi < 4; fi++)
#pragma unroll
      for (int rr = 0; rr < 4; rr++) {
        p1 += acc[fi][ii][rr] * a1v[fi * 4 + rr];
        p2 += acc[fi][ii][rr] * a2v[fi * 4 + rr];
      }
    p1 += __shfl_xor(p1, 16); p1 += __shfl_xor(p1, 32);
    p2 += __shfl_xor(p2, 16); p2 += __shfl_xor(p2, 32);
    if (lane < 16) {
      atomicAdd(&s1[b * NN + ibase + wi + ii * 16 + lane], p1);
      atomicAdd(&s2[b * NN + ibase + wi + ii * 16 + lane], p2);
    }
  }
}

// -------------------------------------------------------------------------
// K2: l[b][j] = sum_i adj*exp(leaky(s1_i+s2_j))  +  packed adj bytes (8 j/bit)
// grid (64 i-chunks of 32, 4 b), 256 threads; thread owns 8 consecutive j.
// -------------------------------------------------------------------------
__global__ __launch_bounds__(256) void k_l(const int* __restrict__ adj,
                                           const float* __restrict__ s1,
                                           const float* __restrict__ s2,
                                           float* __restrict__ l,
                                           u8* __restrict__ pb) {
  const int b = blockIdx.y, i0 = blockIdx.x * 32, t = threadIdx.x;
  const int j8 = t * 8;
  float s2v[8];
  *(float4*)(&s2v[0]) = *(const float4*)(s2 + b * NN + j8);
  *(float4*)(&s2v[4]) = *(const float4*)(s2 + b * NN + j8 + 4);
  float accv[8];
#pragma unroll
  for (int k = 0; k < 8; k++) accv[k] = 0.f;
#pragma unroll 4
  for (int i = 0; i < 32; i++) {
    const int row = i0 + i;
    const int4* ap = (const int4*)(adj + ((size_t)b * NN + row) * NN + j8);
    int4 A0 = ap[0], A1 = ap[1];
    const float s1i = s1[b * NN + row];
    int av[8] = {A0.x, A0.y, A0.z, A0.w, A1.x, A1.y, A1.z, A1.w};
    u32 byte = 0;
#pragma unroll
    for (int k = 0; k < 8; k++) {
      float e = leaky(s1i + s2v[k]);
      float p = __expf(e);
      bool m = av[k] > 0;
      accv[k] += m ? p : 0.f;
      byte |= (m ? 1u : 0u) << k;
    }
    pb[((size_t)b * NN + row) * 256 + t] = (u8)byte;
  }
#pragma unroll
  for (int k = 0; k < 8; k++) atomicAdd(&l[b * NN + j8 + k], accv[k]);
}

// -------------------------------------------------------------------------
// K3: out = leaky( P @ Wh ),  P generated on the fly from packed adj bits.
// BM=64, BN=128, BK=64; grid 512 blocks (XCD-chunk swizzled), 256 threads.
// -------------------------------------------------------------------------
__global__ __launch_bounds__(256) void k_out(const u8* __restrict__ pb,
                                             const float* __restrict__ s1,
                                             const float* __restrict__ s2,
                                             const float* __restrict__ l,
                                             const u16* __restrict__ whT,
                                             float* __restrict__ out) {
  __shared__ __attribute__((aligned(16))) u16 Ps[64][72];
  __shared__ __attribute__((aligned(16))) u16 Bs[128][72];
  const int bid = blockIdx.x;
  const int wg = (bid & 7) * 64 + (bid >> 3);   // XCD-chunked, bijective (512%8==0)
  const int bx = wg & 31, by = (wg >> 5) & 3, bz = wg >> 7;
  const int i0 = bx * 64, f0 = by * 128, b = bz;
  const int tid = threadIdx.x, wave = tid >> 6, lane = tid & 63;
  const int wm = (wave >> 1) * 32, wn = (wave & 1) * 64;

  f32x4 acc[2][4];
#pragma unroll
  for (int x = 0; x < 2; x++)
#pragma unroll
    for (int y = 0; y < 4; y++) acc[x][y] = f32x4{0.f, 0.f, 0.f, 0.f};

  const int pi = tid >> 2, q = tid & 3;
  const float s1i = s1[b * NN + i0 + pi];
  const int c = tid & 7, fr = tid >> 3;
  const u8* pbrow = pb + ((size_t)b * NN + i0 + pi) * 256;

  for (int j0 = 0; j0 < NN; j0 += 64) {
    // stage Bs: whT[f0..+128][j0..+64] (already bf16, 16B vector copies)
#pragma unroll
    for (int p = 0; p < 4; p++) {
      const int f = fr + p * 32;
      *(uint4*)(&Bs[f][c * 8]) = *(const uint4*)(whT + ((size_t)b * FF + f0 + f) * NN + j0 + c * 8);
    }
    // stage Ps: thread owns row pi, 16 j's (q*16..+15); bits from packed adj
    {
      u32 bits = *(const u16*)(pbrow + (j0 >> 3) + q * 2);
#pragma unroll
      for (int k4 = 0; k4 < 4; k4++) {
        const int jj = j0 + q * 16 + k4 * 4;
        float4 s2x = *(const float4*)(s2 + b * NN + jj);
        float4 lx = *(const float4*)(l + b * NN + jj);
        float p0 = ((bits >> (k4 * 4 + 0)) & 1) ? __expf(leaky(s1i + s2x.x)) * __builtin_amdgcn_rcpf(lx.x) : 0.f;
        float p1 = ((bits >> (k4 * 4 + 1)) & 1) ? __expf(leaky(s1i + s2x.y)) * __builtin_amdgcn_rcpf(lx.y) : 0.f;
        float p2 = ((bits >> (k4 * 4 + 2)) & 1) ? __expf(leaky(s1i + s2x.z)) * __builtin_amdgcn_rcpf(lx.z) : 0.f;
        float p3 = ((bits >> (k4 * 4 + 3)) & 1) ? __expf(leaky(s1i + s2x.w)) * __builtin_amdgcn_rcpf(lx.w) : 0.f;
        ushort4 o; o.x = f2bf(p0); o.y = f2bf(p1); o.z = f2bf(p2); o.w = f2bf(p3);
        *(ushort4*)(&Ps[pi][q * 16 + k4 * 4]) = o;
      }
    }
    __syncthreads();
    {
      const int r = lane & 15, kq = lane >> 4;
#pragma unroll
      for (int kk = 0; kk < 2; kk++) {
        bf16x8 af[2], bfv[4];
#pragma unroll
        for (int mi = 0; mi < 2; mi++) af[mi] = *(const bf16x8*)(&Ps[wm + mi * 16 + r][kk * 32 + kq * 8]);
#pragma unroll
        for (int ni = 0; ni < 4; ni++) bfv[ni] = *(const bf16x8*)(&Bs[wn + ni * 16 + r][kk * 32 + kq * 8]);
#pragma unroll
        for (int mi = 0; mi < 2; mi++)
#pragma unroll
          for (int ni = 0; ni < 4; ni++)
            acc[mi][ni] = __builtin_amdgcn_mfma_f32_16x16x32_bf16(af[mi], bfv[ni], acc[mi][ni], 0, 0, 0);
      }
    }
    __syncthreads();
  }
  const int r = lane & 15, rg = lane >> 4;
#pragma unroll
  for (int mi = 0; mi < 2; mi++)
#pragma unroll
    for (int ni = 0; ni < 4; ni++) {
      const int f = f0 + wn + ni * 16 + r;
#pragma unroll
      for (int rr = 0; rr < 4; rr++) {
        const int i = i0 + wm + mi * 16 + rg * 4 + rr;
        out[((size_t)b * NN + i) * FF + f] = leaky(acc[mi][ni][rr]);
      }
    }
}

extern "C" void kernel_launch(void* const* d_in, const int* in_sizes, int n_in,
                              void* d_out, int out_size, void* d_ws, size_t ws_size,
                              hipStream_t stream) {
  const float* h = (const float*)d_in[0];
  const float* W = (const float*)d_in[1];
  const float* a = (const float*)d_in[2];
  const int* adj = (const int*)d_in[3];
  float* out = (float*)d_out;

  char* ws = (char*)d_ws;
  u16* whT = (u16*)ws;                              // 8 MiB
  float* s1 = (float*)(ws + (size_t)8388608);       // 32 KiB
  float* s2 = s1 + BB * NN;                         // 32 KiB
  float* lsum = s2 + BB * NN;                       // 32 KiB
  u8* pb = (u8*)(lsum + BB * NN);                   // 2 MiB packed adj

  hipMemsetAsync(s1, 0, (size_t)3 * BB * NN * sizeof(float), stream);

  k_wh<<<dim3(64, 4), 256, 0, stream>>>(h, W, a, whT, s1, s2);
  k_l<<<dim3(64, 4), 256, 0, stream>>>(adj, s1, s2, lsum, pb);
  k_out<<<dim3(512), 256, 0, stream>>>(pb, s1, s2, lsum, whT, out);
}

// Round 4
// 127.141 us; speedup vs baseline: 1.3602x; 1.3602x over previous
//
#include <hip/hip_runtime.h>

#define BB 4
#define NN 2048
#define FF 512
#define ALPHA 0.2f

typedef unsigned short u16;
typedef unsigned int u32;
typedef __attribute__((ext_vector_type(8))) short bf16x8;
typedef __attribute__((ext_vector_type(4))) float f32x4;

__device__ __forceinline__ u16 f2bf(float x) {
  union { float f; u32 u; } v; v.f = x;
  u32 r = v.u + 0x7fffu + ((v.u >> 16) & 1u);
  return (u16)(r >> 16);
}
__device__ __forceinline__ float bf2f(u16 u) {
  union { u32 i; float f; } v; v.i = ((u32)u) << 16; return v.f;
}
__device__ __forceinline__ float leaky(float x) { return x >= 0.f ? x : ALPHA * x; }

// -------------------------------------------------------------------------
// K1: whT[b][f][i] = (h@W)^T bf16  +  fused s1/s2
// -------------------------------------------------------------------------
__global__ __launch_bounds__(256) void k_wh(const float* __restrict__ h,
                                            const float* __restrict__ W,
                                            const float* __restrict__ a,
                                            u16* __restrict__ whT,
                                            float* __restrict__ s1,
                                            float* __restrict__ s2) {
  __shared__ __attribute__((aligned(16))) u16 As[128][40];
  __shared__ __attribute__((aligned(16))) u16 Bs[128][40];
  const int m0 = blockIdx.x * 128, f0 = blockIdx.y * 128;
  const int tid = threadIdx.x, wave = tid >> 6, lane = tid & 63;
  const int wf = (wave >> 1) * 64, wi = (wave & 1) * 64;

  f32x4 acc[4][4];
#pragma unroll
  for (int x = 0; x < 4; x++)
#pragma unroll
    for (int y = 0; y < 4; y++) acc[x][y] = f32x4{0.f, 0.f, 0.f, 0.f};

  for (int k0 = 0; k0 < FF; k0 += 32) {
    {
      const int kc = tid & 7, ib = tid >> 3;
#pragma unroll
      for (int p = 0; p < 4; p++) {
        const int i = ib + p * 32;
        float4 v = *(const float4*)(h + (size_t)(m0 + i) * FF + k0 + kc * 4);
        ushort4 o; o.x = f2bf(v.x); o.y = f2bf(v.y); o.z = f2bf(v.z); o.w = f2bf(v.w);
        *(ushort4*)(&As[i][kc * 4]) = o;
      }
    }
    {
      const int fc = tid & 31, kb = tid >> 5;
#pragma unroll
      for (int p = 0; p < 4; p++) {
        const int k = kb + p * 8;
        float4 v = *(const float4*)(W + (size_t)(k0 + k) * FF + f0 + fc * 4);
        Bs[fc * 4 + 0][k] = f2bf(v.x);
        Bs[fc * 4 + 1][k] = f2bf(v.y);
        Bs[fc * 4 + 2][k] = f2bf(v.z);
        Bs[fc * 4 + 3][k] = f2bf(v.w);
      }
    }
    __syncthreads();
    {
      const int r = lane & 15, kq = lane >> 4;
      bf16x8 wfr[4], hfr[4];
#pragma unroll
      for (int fi = 0; fi < 4; fi++) wfr[fi] = *(const bf16x8*)(&Bs[wf + fi * 16 + r][kq * 8]);
#pragma unroll
      for (int ii = 0; ii < 4; ii++) hfr[ii] = *(const bf16x8*)(&As[wi + ii * 16 + r][kq * 8]);
#pragma unroll
      for (int fi = 0; fi < 4; fi++)
#pragma unroll
        for (int ii = 0; ii < 4; ii++)
          acc[fi][ii] = __builtin_amdgcn_mfma_f32_16x16x32_bf16(wfr[fi], hfr[ii], acc[fi][ii], 0, 0, 0);
    }
    __syncthreads();
  }

  const int b = m0 >> 11, ibase = m0 & (NN - 1);
  const int r = lane & 15, rg = lane >> 4;
  float a1v[16], a2v[16];
#pragma unroll
  for (int fi = 0; fi < 4; fi++)
#pragma unroll
    for (int rr = 0; rr < 4; rr++) {
      const int f = f0 + wf + fi * 16 + rg * 4 + rr;
      a1v[fi * 4 + rr] = a[f];
      a2v[fi * 4 + rr] = a[FF + f];
    }
#pragma unroll
  for (int fi = 0; fi < 4; fi++)
#pragma unroll
    for (int ii = 0; ii < 4; ii++)
#pragma unroll
      for (int rr = 0; rr < 4; rr++) {
        const int f = f0 + wf + fi * 16 + rg * 4 + rr;
        whT[((size_t)b * FF + f) * NN + ibase + wi + ii * 16 + r] = f2bf(acc[fi][ii][rr]);
      }
#pragma unroll
  for (int ii = 0; ii < 4; ii++) {
    float p1 = 0.f, p2 = 0.f;
#pragma unroll
    for (int fi = 0; fi < 4; fi++)
#pragma unroll
      for (int rr = 0; rr < 4; rr++) {
        p1 += acc[fi][ii][rr] * a1v[fi * 4 + rr];
        p2 += acc[fi][ii][rr] * a2v[fi * 4 + rr];
      }
    p1 += __shfl_xor(p1, 16); p1 += __shfl_xor(p1, 32);
    p2 += __shfl_xor(p2, 16); p2 += __shfl_xor(p2, 32);
    if (lane < 16) {
      atomicAdd(&s1[b * NN + ibase + wi + ii * 16 + lane], p1);
      atomicAdd(&s2[b * NN + ibase + wi + ii * 16 + lane], p2);
    }
  }
}

// -------------------------------------------------------------------------
// K2: stream adj once; l[b][j] += sum_i p; materialize P_u[b][i][j] bf16.
// -------------------------------------------------------------------------
__global__ __launch_bounds__(256) void k_l(const int* __restrict__ adj,
                                           const float* __restrict__ s1,
                                           const float* __restrict__ s2,
                                           float* __restrict__ l,
                                           u16* __restrict__ P) {
  const int b = blockIdx.y, i0 = blockIdx.x * 32, t = threadIdx.x;
  const int j8 = t * 8;
  float s2v[8];
  *(float4*)(&s2v[0]) = *(const float4*)(s2 + b * NN + j8);
  *(float4*)(&s2v[4]) = *(const float4*)(s2 + b * NN + j8 + 4);
  float accv[8];
#pragma unroll
  for (int k = 0; k < 8; k++) accv[k] = 0.f;
#pragma unroll 2
  for (int i = 0; i < 32; i++) {
    const int row = i0 + i;
    const int4* ap = (const int4*)(adj + ((size_t)b * NN + row) * NN + j8);
    int4 A0 = ap[0], A1 = ap[1];
    const float s1i = s1[b * NN + row];
    int av[8] = {A0.x, A0.y, A0.z, A0.w, A1.x, A1.y, A1.z, A1.w};
    union { uint4 q; u16 s[8]; } o;
#pragma unroll
    for (int k = 0; k < 8; k++) {
      float e = leaky(s1i + s2v[k]);
      float p = (av[k] > 0) ? __expf(e) : 0.f;
      accv[k] += p;
      o.s[k] = f2bf(p);
    }
    *(uint4*)(P + ((size_t)b * NN + row) * NN + j8) = o.q;
  }
#pragma unroll
  for (int k = 0; k < 8; k++) atomicAdd(&l[b * NN + j8 + k], accv[k]);
}

// -------------------------------------------------------------------------
// K3: whT[b][f][j] *= 1/l[b][j]   (in-place; EXACTLY 524288 8-u16 units)
// -------------------------------------------------------------------------
__global__ __launch_bounds__(256) void k_scale(u16* __restrict__ whT,
                                               const float* __restrict__ l) {
  const int e = blockIdx.x * 256 + threadIdx.x;  // unit = 8 u16; e < 524288
  const int j8 = (e * 8) & (NN - 1);
  const int b = e >> 17;  // 512*2048/8 = 2^17 units per batch
  u16* p = whT + (size_t)e * 8;
  union { uint4 q; u16 s[8]; } v;
  v.q = *(const uint4*)p;
  float4 l0 = *(const float4*)(l + b * NN + j8);
  float4 l1 = *(const float4*)(l + b * NN + j8 + 4);
  float rl_[8] = {__builtin_amdgcn_rcpf(l0.x), __builtin_amdgcn_rcpf(l0.y),
                  __builtin_amdgcn_rcpf(l0.z), __builtin_amdgcn_rcpf(l0.w),
                  __builtin_amdgcn_rcpf(l1.x), __builtin_amdgcn_rcpf(l1.y),
                  __builtin_amdgcn_rcpf(l1.z), __builtin_amdgcn_rcpf(l1.w)};
#pragma unroll
  for (int k = 0; k < 8; k++) v.s[k] = f2bf(bf2f(v.s[k]) * rl_[k]);
  *(uint4*)p = v.q;
}

// -------------------------------------------------------------------------
// K4: out = leaky( P_u @ Wh' ) — pure bf16 GEMM, m97-style.
// 128x128 tile, BK=64, 4 waves, dbuf global_load_lds(16B), 256 blocks.
// -------------------------------------------------------------------------
__device__ __forceinline__ void stage8(const u16* ga0, const u16* gb0,
                                       u16* lA, u16* lB, int off16) {
#pragma unroll
  for (int p = 0; p < 4; p++) {
    __builtin_amdgcn_global_load_lds(
        (const __attribute__((address_space(1))) void*)(ga0 + (size_t)p * 8 * NN + off16),
        (__attribute__((address_space(3))) void*)(lA + p * 512), 16, 0, 0);
    __builtin_amdgcn_global_load_lds(
        (const __attribute__((address_space(1))) void*)(gb0 + (size_t)p * 8 * NN + off16),
        (__attribute__((address_space(3))) void*)(lB + p * 512), 16, 0, 0);
  }
}

__global__ __launch_bounds__(256) void k_out(const u16* __restrict__ P,
                                             const u16* __restrict__ whS,
                                             float* __restrict__ out) {
  __shared__ __attribute__((aligned(16))) u16 As[2][128][64];
  __shared__ __attribute__((aligned(16))) u16 Bs[2][128][64];
  const int p0 = blockIdx.x;
  const int L = (p0 & 7) * 32 + (p0 >> 3);  // XCD-chunked, bijective (256 = 8*32)
  const int b = L >> 6, it = (L >> 2) & 15, ft = L & 3;
  const int i0 = it * 128, f0 = ft * 128;
  const int tid = threadIdx.x, wave = tid >> 6, lane = tid & 63;
  const int wm = (wave >> 1) * 64, wn = (wave & 1) * 64;

  // per-lane global bases (inst p=0): row = wave*32 + lane/8, col16 = lane%8
  const int srow = lane >> 3, scol = (lane & 7) * 8;
  const u16* gA0 = P + ((size_t)(b * NN + i0 + wave * 32 + srow)) * NN + scol;
  const u16* gB0 = whS + ((size_t)(b * FF + f0 + wave * 32 + srow)) * NN + scol;

  f32x4 acc[4][4];
#pragma unroll
  for (int x = 0; x < 4; x++)
#pragma unroll
    for (int y = 0; y < 4; y++) acc[x][y] = f32x4{0.f, 0.f, 0.f, 0.f};

  stage8(gA0, gB0, &As[0][wave * 32][0], &Bs[0][wave * 32][0], 0);
  __syncthreads();

  int cur = 0;
  const int r = lane & 15, kq = lane >> 4;
  for (int t = 0; t < 32; t++) {
    if (t < 31)
      stage8(gA0, gB0, &As[cur ^ 1][wave * 32][0], &Bs[cur ^ 1][wave * 32][0], (t + 1) * 64);
#pragma unroll
    for (int kk = 0; kk < 2; kk++) {
      bf16x8 af[4], bv[4];
#pragma unroll
      for (int mi = 0; mi < 4; mi++)
        af[mi] = *(const bf16x8*)(&As[cur][wm + mi * 16 + r][kk * 32 + kq * 8]);
#pragma unroll
      for (int ni = 0; ni < 4; ni++)
        bv[ni] = *(const bf16x8*)(&Bs[cur][wn + ni * 16 + r][kk * 32 + kq * 8]);
#pragma unroll
      for (int mi = 0; mi < 4; mi++)
#pragma unroll
        for (int ni = 0; ni < 4; ni++)
          acc[mi][ni] = __builtin_amdgcn_mfma_f32_16x16x32_bf16(af[mi], bv[ni], acc[mi][ni], 0, 0, 0);
    }
    __syncthreads();  // drains vmcnt (next-tile stage) + lgkmcnt, then barrier
    cur ^= 1;
  }

  const int rg = lane >> 4;
#pragma unroll
  for (int mi = 0; mi < 4; mi++)
#pragma unroll
    for (int ni = 0; ni < 4; ni++) {
      const int f = f0 + wn + ni * 16 + r;
#pragma unroll
      for (int rr = 0; rr < 4; rr++) {
        const int i = i0 + wm + mi * 16 + rg * 4 + rr;
        out[((size_t)b * NN + i) * FF + f] = leaky(acc[mi][ni][rr]);
      }
    }
}

extern "C" void kernel_launch(void* const* d_in, const int* in_sizes, int n_in,
                              void* d_out, int out_size, void* d_ws, size_t ws_size,
                              hipStream_t stream) {
  const float* h = (const float*)d_in[0];
  const float* W = (const float*)d_in[1];
  const float* a = (const float*)d_in[2];
  const int* adj = (const int*)d_in[3];
  float* out = (float*)d_out;

  char* ws = (char*)d_ws;
  u16* whT = (u16*)ws;                                   // 8 MiB [b][f][j]
  float* s1 = (float*)(ws + (size_t)8388608);            // 32 KiB
  float* s2 = s1 + BB * NN;                              // 32 KiB
  float* lsum = s2 + BB * NN;                            // 32 KiB
  u16* P = (u16*)(ws + (size_t)8388608 + 131072);        // 33.5 MiB [b][i][j]

  hipMemsetAsync(s1, 0, (size_t)3 * BB * NN * sizeof(float), stream);

  k_wh<<<dim3(64, 4), 256, 0, stream>>>(h, W, a, whT, s1, s2);
  k_l<<<dim3(64, 4), 256, 0, stream>>>(adj, s1, s2, lsum, P);
  k_scale<<<dim3(2048), 256, 0, stream>>>(whT, lsum);   // 524288 units exactly
  k_out<<<dim3(256), 256, 0, stream>>>(P, whT, out);
}

// Round 5
// 114.394 us; speedup vs baseline: 1.5118x; 1.1114x over previous
//
#include <hip/hip_runtime.h>

#define BB 4
#define NN 2048
#define FF 512
#define ALPHA 0.2f

typedef unsigned short u16;
typedef unsigned int u32;
typedef __attribute__((ext_vector_type(8))) short bf16x8;
typedef __attribute__((ext_vector_type(4))) float f32x4;

__device__ __forceinline__ u16 f2bf(float x) {
  union { float f; u32 u; } v; v.f = x;
  u32 r = v.u + 0x7fffu + ((v.u >> 16) & 1u);
  return (u16)(r >> 16);
}
__device__ __forceinline__ float leaky(float x) { return x >= 0.f ? x : ALPHA * x; }

// -------------------------------------------------------------------------
// K0: wa1[k] = sum_f W[k][f]*a[f], wa2[k] = sum_f W[k][f]*a[FF+f]  (fp32)
// 128 blocks x 4 waves, one wave per k-row.
// -------------------------------------------------------------------------
__global__ __launch_bounds__(256) void k_wa(const float* __restrict__ W,
                                            const float* __restrict__ a,
                                            float* __restrict__ wa1,
                                            float* __restrict__ wa2) {
  const int wave = threadIdx.x >> 6, lane = threadIdx.x & 63;
  const int k = blockIdx.x * 4 + wave;
  const int f0 = lane * 8;
  float4 w0 = *(const float4*)(W + (size_t)k * FF + f0);
  float4 w1 = *(const float4*)(W + (size_t)k * FF + f0 + 4);
  float4 p0 = *(const float4*)(a + f0);
  float4 p1 = *(const float4*)(a + f0 + 4);
  float4 q0 = *(const float4*)(a + FF + f0);
  float4 q1 = *(const float4*)(a + FF + f0 + 4);
  float d1 = w0.x*p0.x + w0.y*p0.y + w0.z*p0.z + w0.w*p0.w
           + w1.x*p1.x + w1.y*p1.y + w1.z*p1.z + w1.w*p1.w;
  float d2 = w0.x*q0.x + w0.y*q0.y + w0.z*q0.z + w0.w*q0.w
           + w1.x*q1.x + w1.y*q1.y + w1.z*q1.z + w1.w*q1.w;
#pragma unroll
  for (int o = 32; o; o >>= 1) { d1 += __shfl_xor(d1, o); d2 += __shfl_xor(d2, o); }
  if (lane == 0) { wa1[k] = d1; wa2[k] = d2; }
}

// -------------------------------------------------------------------------
// K0b: s1[row] = h[row]·wa1, s2[row] = h[row]·wa2  (fp32, one wave per row)
// -------------------------------------------------------------------------
__global__ __launch_bounds__(256) void k_s(const float* __restrict__ h,
                                           const float* __restrict__ wa1,
                                           const float* __restrict__ wa2,
                                           float* __restrict__ s1,
                                           float* __restrict__ s2) {
  const int wave = threadIdx.x >> 6, lane = threadIdx.x & 63;
  const int row = blockIdx.x * 4 + wave;  // 0..8191
  const int f0 = lane * 8;
  float4 h0 = *(const float4*)(h + (size_t)row * FF + f0);
  float4 h1 = *(const float4*)(h + (size_t)row * FF + f0 + 4);
  float4 p0 = *(const float4*)(wa1 + f0);
  float4 p1 = *(const float4*)(wa1 + f0 + 4);
  float4 q0 = *(const float4*)(wa2 + f0);
  float4 q1 = *(const float4*)(wa2 + f0 + 4);
  float d1 = h0.x*p0.x + h0.y*p0.y + h0.z*p0.z + h0.w*p0.w
           + h1.x*p1.x + h1.y*p1.y + h1.z*p1.z + h1.w*p1.w;
  float d2 = h0.x*q0.x + h0.y*q0.y + h0.z*q0.z + h0.w*q0.w
           + h1.x*q1.x + h1.y*q1.y + h1.z*q1.z + h1.w*q1.w;
#pragma unroll
  for (int o = 32; o; o >>= 1) { d1 += __shfl_xor(d1, o); d2 += __shfl_xor(d2, o); }
  if (lane == 0) { s1[row] = d1; s2[row] = d2; }
}

// -------------------------------------------------------------------------
// K2: stream adj once; l[b][j] += sum_i p; materialize P_u[b][i][j] bf16.
// -------------------------------------------------------------------------
__global__ __launch_bounds__(256) void k_l(const int* __restrict__ adj,
                                           const float* __restrict__ s1,
                                           const float* __restrict__ s2,
                                           float* __restrict__ l,
                                           u16* __restrict__ P) {
  const int b = blockIdx.y, i0 = blockIdx.x * 32, t = threadIdx.x;
  const int j8 = t * 8;
  float s2v[8];
  *(float4*)(&s2v[0]) = *(const float4*)(s2 + b * NN + j8);
  *(float4*)(&s2v[4]) = *(const float4*)(s2 + b * NN + j8 + 4);
  float accv[8];
#pragma unroll
  for (int k = 0; k < 8; k++) accv[k] = 0.f;
#pragma unroll 4
  for (int i = 0; i < 32; i++) {
    const int row = i0 + i;
    const int4* ap = (const int4*)(adj + ((size_t)b * NN + row) * NN + j8);
    int4 A0 = ap[0], A1 = ap[1];
    const float s1i = s1[b * NN + row];
    int av[8] = {A0.x, A0.y, A0.z, A0.w, A1.x, A1.y, A1.z, A1.w};
    union { uint4 q; u16 s[8]; } o;
#pragma unroll
    for (int k = 0; k < 8; k++) {
      float e = leaky(s1i + s2v[k]);
      float p = (av[k] > 0) ? __expf(e) : 0.f;
      accv[k] += p;
      o.s[k] = f2bf(p);
    }
    *(uint4*)(P + ((size_t)b * NN + row) * NN + j8) = o.q;
  }
#pragma unroll
  for (int k = 0; k < 8; k++) atomicAdd(&l[b * NN + j8 + k], accv[k]);
}

// -------------------------------------------------------------------------
// K3: whT[b][f][i] = bf16( (h@W)[i][f] * 1/l[b][i] )   (scale folded in)
// -------------------------------------------------------------------------
__global__ __launch_bounds__(256) void k_wh(const float* __restrict__ h,
                                            const float* __restrict__ W,
                                            const float* __restrict__ l,
                                            u16* __restrict__ whT) {
  __shared__ __attribute__((aligned(16))) u16 As[128][40];
  __shared__ __attribute__((aligned(16))) u16 Bs[128][40];
  const int m0 = blockIdx.x * 128, f0 = blockIdx.y * 128;
  const int tid = threadIdx.x, wave = tid >> 6, lane = tid & 63;
  const int wf = (wave >> 1) * 64, wi = (wave & 1) * 64;

  f32x4 acc[4][4];
#pragma unroll
  for (int x = 0; x < 4; x++)
#pragma unroll
    for (int y = 0; y < 4; y++) acc[x][y] = f32x4{0.f, 0.f, 0.f, 0.f};

  for (int k0 = 0; k0 < FF; k0 += 32) {
    {
      const int kc = tid & 7, ib = tid >> 3;
#pragma unroll
      for (int p = 0; p < 4; p++) {
        const int i = ib + p * 32;
        float4 v = *(const float4*)(h + (size_t)(m0 + i) * FF + k0 + kc * 4);
        ushort4 o; o.x = f2bf(v.x); o.y = f2bf(v.y); o.z = f2bf(v.z); o.w = f2bf(v.w);
        *(ushort4*)(&As[i][kc * 4]) = o;
      }
    }
    {
      const int fc = tid & 31, kb = tid >> 5;
#pragma unroll
      for (int p = 0; p < 4; p++) {
        const int k = kb + p * 8;
        float4 v = *(const float4*)(W + (size_t)(k0 + k) * FF + f0 + fc * 4);
        Bs[fc * 4 + 0][k] = f2bf(v.x);
        Bs[fc * 4 + 1][k] = f2bf(v.y);
        Bs[fc * 4 + 2][k] = f2bf(v.z);
        Bs[fc * 4 + 3][k] = f2bf(v.w);
      }
    }
    __syncthreads();
    {
      const int r = lane & 15, kq = lane >> 4;
      bf16x8 wfr[4], hfr[4];
#pragma unroll
      for (int fi = 0; fi < 4; fi++) wfr[fi] = *(const bf16x8*)(&Bs[wf + fi * 16 + r][kq * 8]);
#pragma unroll
      for (int ii = 0; ii < 4; ii++) hfr[ii] = *(const bf16x8*)(&As[wi + ii * 16 + r][kq * 8]);
#pragma unroll
      for (int fi = 0; fi < 4; fi++)
#pragma unroll
        for (int ii = 0; ii < 4; ii++)
          acc[fi][ii] = __builtin_amdgcn_mfma_f32_16x16x32_bf16(wfr[fi], hfr[ii], acc[fi][ii], 0, 0, 0);
    }
    __syncthreads();
  }

  const int b = m0 >> 11, ibase = m0 & (NN - 1);
  const int r = lane & 15, rg = lane >> 4;
#pragma unroll
  for (int ii = 0; ii < 4; ii++) {
    const int icol = ibase + wi + ii * 16 + r;
    const float rl = __builtin_amdgcn_rcpf(l[b * NN + icol]);
#pragma unroll
    for (int fi = 0; fi < 4; fi++)
#pragma unroll
      for (int rr = 0; rr < 4; rr++) {
        const int f = f0 + wf + fi * 16 + rg * 4 + rr;
        whT[((size_t)b * FF + f) * NN + icol] = f2bf(acc[fi][ii][rr] * rl);
      }
  }
}

// -------------------------------------------------------------------------
// K4: out = leaky( P_u @ Wh' ) — bf16 GEMM, T2 swizzle + T4 counted vmcnt.
// 128x128 tile, BK=64, 4 waves, dbuf global_load_lds(16B), 256 blocks.
// -------------------------------------------------------------------------
__device__ __forceinline__ void stage8(const u16* ga0, const u16* gb0,
                                       u16* lA, u16* lB, int off16) {
#pragma unroll
  for (int p = 0; p < 4; p++) {
    __builtin_amdgcn_global_load_lds(
        (const __attribute__((address_space(1))) void*)(ga0 + (size_t)p * 8 * NN + off16),
        (__attribute__((address_space(3))) void*)(lA + p * 512), 16, 0, 0);
    __builtin_amdgcn_global_load_lds(
        (const __attribute__((address_space(1))) void*)(gb0 + (size_t)p * 8 * NN + off16),
        (__attribute__((address_space(3))) void*)(lB + p * 512), 16, 0, 0);
  }
}

__global__ __launch_bounds__(256) void k_out(const u16* __restrict__ P,
                                             const u16* __restrict__ whS,
                                             float* __restrict__ out) {
  __shared__ __attribute__((aligned(16))) u16 As[2][128][64];
  __shared__ __attribute__((aligned(16))) u16 Bs[2][128][64];
  const int p0 = blockIdx.x;
  const int L = (p0 & 7) * 32 + (p0 >> 3);  // XCD-chunked, bijective (256 = 8*32)
  const int b = L >> 6, it = (L >> 2) & 15, ft = L & 3;
  const int i0 = it * 128, f0 = ft * 128;
  const int tid = threadIdx.x, wave = tid >> 6, lane = tid & 63;
  const int wm = (wave >> 1) * 64, wn = (wave & 1) * 64;

  // pre-swizzled global source column (rule #21: inverse-swz SOURCE, swz READ)
  const int srow = lane >> 3;
  const int scol = (((lane & 7) ^ (srow & 7)) << 3);  // u16 units
  const u16* gA0 = P + ((size_t)(b * NN + i0 + wave * 32 + srow)) * NN + scol;
  const u16* gB0 = whS + ((size_t)(b * FF + f0 + wave * 32 + srow)) * NN + scol;

  f32x4 acc[4][4];
#pragma unroll
  for (int x = 0; x < 4; x++)
#pragma unroll
    for (int y = 0; y < 4; y++) acc[x][y] = f32x4{0.f, 0.f, 0.f, 0.f};

  stage8(gA0, gB0, &As[0][wave * 32][0], &Bs[0][wave * 32][0], 0);

  int cur = 0;
  const int r = lane & 15, kq = lane >> 4;
  const int sx = (r & 7) << 3;  // read-side XOR (u16 units)
  for (int t = 0; t < 32; t++) {
    if (t < 31) {
      stage8(gA0, gB0, &As[cur ^ 1][wave * 32][0], &Bs[cur ^ 1][wave * 32][0], (t + 1) * 64);
      asm volatile("s_waitcnt vmcnt(8)" ::: "memory");  // drain cur's 8, keep next's 8 in flight
    } else {
      asm volatile("s_waitcnt vmcnt(0)" ::: "memory");
    }
    __builtin_amdgcn_s_barrier();  // all waves: buf[cur] fully staged
#pragma unroll
    for (int kk = 0; kk < 2; kk++) {
      bf16x8 af[4], bv[4];
#pragma unroll
      for (int mi = 0; mi < 4; mi++)
        af[mi] = *(const bf16x8*)(&As[cur][wm + mi * 16 + r][(kk * 32 + kq * 8) ^ sx]);
#pragma unroll
      for (int ni = 0; ni < 4; ni++)
        bv[ni] = *(const bf16x8*)(&Bs[cur][wn + ni * 16 + r][(kk * 32 + kq * 8) ^ sx]);
#pragma unroll
      for (int mi = 0; mi < 4; mi++)
#pragma unroll
        for (int ni = 0; ni < 4; ni++)
          acc[mi][ni] = __builtin_amdgcn_mfma_f32_16x16x32_bf16(af[mi], bv[ni], acc[mi][ni], 0, 0, 0);
    }
    __builtin_amdgcn_s_barrier();  // close reads of buf[cur] before next stage overwrites
    cur ^= 1;
  }

  const int rg = lane >> 4;
#pragma unroll
  for (int mi = 0; mi < 4; mi++)
#pragma unroll
    for (int ni = 0; ni < 4; ni++) {
      const int f = f0 + wn + ni * 16 + r;
#pragma unroll
      for (int rr = 0; rr < 4; rr++) {
        const int i = i0 + wm + mi * 16 + rg * 4 + rr;
        out[((size_t)b * NN + i) * FF + f] = leaky(acc[mi][ni][rr]);
      }
    }
}

extern "C" void kernel_launch(void* const* d_in, const int* in_sizes, int n_in,
                              void* d_out, int out_size, void* d_ws, size_t ws_size,
                              hipStream_t stream) {
  const float* h = (const float*)d_in[0];
  const float* W = (const float*)d_in[1];
  const float* a = (const float*)d_in[2];
  const int* adj = (const int*)d_in[3];
  float* out = (float*)d_out;

  char* ws = (char*)d_ws;
  u16* whT = (u16*)ws;                                    // 8 MiB [b][f][i]
  u16* P = (u16*)(ws + (size_t)8388608);                  // 33.5 MiB [b][i][j]
  float* s1 = (float*)(ws + (size_t)8388608 + 33554432);  // 32 KiB
  float* s2 = s1 + BB * NN;                               // 32 KiB
  float* lsum = s2 + BB * NN;                             // 32 KiB
  float* wa1 = lsum + BB * NN;                            // 2 KiB
  float* wa2 = wa1 + FF;                                  // 2 KiB

  hipMemsetAsync(lsum, 0, (size_t)BB * NN * sizeof(float), stream);

  k_wa<<<dim3(128), 256, 0, stream>>>(W, a, wa1, wa2);
  k_s<<<dim3(2048), 256, 0, stream>>>(h, wa1, wa2, s1, s2);
  k_l<<<dim3(64, 4), 256, 0, stream>>>(adj, s1, s2, lsum, P);
  k_wh<<<dim3(64, 4), 256, 0, stream>>>(h, W, lsum, whT);
  k_out<<<dim3(256), 256, 0, stream>>>(P, whT, out);
}